// Round 1
// baseline (878.867 us; speedup 1.0000x reference)
//
#include <hip/hip_runtime.h>
#include <math.h>

// Problem constants (B=1)
#define TT 2048   // sequence length
#define CC 1024   // channels
#define HH 16     // heads
#define DD 64     // head dim
#define N3 3072   // 3*C
#define QT 8      // queries per attention block

typedef unsigned short u16;
typedef __bf16 bf16x8 __attribute__((ext_vector_type(8)));
typedef float f32x4 __attribute__((ext_vector_type(4)));
typedef unsigned short u16x8 __attribute__((ext_vector_type(8)));

__device__ __forceinline__ u16 bf16_rne(float f) {
  unsigned u = __float_as_uint(f);
  u += 0x7FFFu + ((u >> 16) & 1u);
  return (u16)(u >> 16);
}
__device__ __forceinline__ float bf16f(u16 h) {
  return __uint_as_float(((unsigned)h) << 16);
}

// ---- fp32 -> bf16 elementwise (float4 per thread) ----
__global__ void k_cvt_bf16(const float* __restrict__ x, u16* __restrict__ o, int n4) {
  int i = blockIdx.x * blockDim.x + threadIdx.x;
  if (i >= n4) return;
  float4 v = ((const float4*)x)[i];
  u16 r0 = bf16_rne(v.x), r1 = bf16_rne(v.y), r2 = bf16_rne(v.z), r3 = bf16_rne(v.w);
  ushort4 r; r.x = r0; r.y = r1; r.z = r2; r.w = r3;
  ((ushort4*)o)[i] = r;
}

// ---- w[K][N] fp32 -> wt[N][K] bf16, 32x32 LDS tile ----
__global__ void k_transpose_bf16(const float* __restrict__ w, u16* __restrict__ wt,
                                 int K, int N) {
  __shared__ u16 tile[32][33];  // +1 pad: no bank conflicts
  int n0 = blockIdx.x * 32, k0 = blockIdx.y * 32;
  int tx = threadIdx.x, ty = threadIdx.y;  // (32, 8)
  for (int r = ty; r < 32; r += 8)
    tile[r][tx] = bf16_rne(w[(size_t)(k0 + r) * N + n0 + tx]);
  __syncthreads();
  for (int r = ty; r < 32; r += 8)
    wt[(size_t)(n0 + r) * K + k0 + tx] = tile[tx][r];
}

// ---- bf16 MFMA GEMM: C[M][N] = A[M][K] * Bt[N][K]^T, fp32 out ----
// 64x64 tile, BK=32, 4 waves (each wave: 16-row strip x 64 cols).
// mfma_f32_16x16x32_bf16 layouts (HW-verified per guide):
//   A frag: m=lane&15, k=(lane>>4)*8+j ; B frag: n=lane&15, k=(lane>>4)*8+j
//   C/D:    col=lane&15, row=(lane>>4)*4+reg
__global__ __launch_bounds__(256) void k_gemm_bf16(
    const u16* __restrict__ A, const u16* __restrict__ Bt,
    float* __restrict__ C, int M, int N, int K) {
  __shared__ u16 As[64][32];
  __shared__ u16 Bs[64][32];
  const int tm = blockIdx.y * 64, tn = blockIdx.x * 64;
  const int tid = threadIdx.x;
  const int lane = tid & 63, wave = tid >> 6;
  const int col = lane & 15, quad = lane >> 4;
  const int srow = tid >> 2, scol = (tid & 3) * 8;  // 16B per thread per tile

  f32x4 zero = {0.f, 0.f, 0.f, 0.f};
  f32x4 acc[4] = {zero, zero, zero, zero};

  for (int k0 = 0; k0 < K; k0 += 32) {
    *(u16x8*)&As[srow][scol] = *(const u16x8*)&A[(size_t)(tm + srow) * K + k0 + scol];
    *(u16x8*)&Bs[srow][scol] = *(const u16x8*)&Bt[(size_t)(tn + srow) * K + k0 + scol];
    __syncthreads();
    bf16x8 af = __builtin_bit_cast(bf16x8, *(const u16x8*)&As[wave * 16 + col][quad * 8]);
#pragma unroll
    for (int nt = 0; nt < 4; nt++) {
      bf16x8 bfr = __builtin_bit_cast(bf16x8, *(const u16x8*)&Bs[nt * 16 + col][quad * 8]);
      acc[nt] = __builtin_amdgcn_mfma_f32_16x16x32_bf16(af, bfr, acc[nt], 0, 0, 0);
    }
    __syncthreads();
  }
#pragma unroll
  for (int nt = 0; nt < 4; nt++)
#pragma unroll
    for (int r = 0; r < 4; r++)
      C[(size_t)(tm + wave * 16 + quad * 4 + r) * N + tn + nt * 16 + col] = acc[nt][r];
}

// ---- RoPE + reorg: qkv[T][3*C] -> qr/kr/vr [H][T][D] (rope on q,k) ----
__global__ void k_rope(const float* __restrict__ qkv, float* __restrict__ qr,
                       float* __restrict__ kr, float* __restrict__ vr) {
  int idx = blockIdx.x * 256 + threadIdx.x;  // over T*H*D = 2M
  if (idx >= TT * HH * DD) return;
  int d = idx & 63;
  int h = (idx >> 6) & 15;
  int t = idx >> 10;
  const float* row = qkv + (size_t)t * N3 + h * DD;
  int i = d >> 1;
  // inv_freq = theta^(-2i/D); ang = t * inv_freq (fp32, matching reference)
  float inv_freq = exp2f(-(float)(2 * i) * (1.0f / 64.0f) * 13.2877123795494f); // log2(1e4)
  float ang = (float)t * inv_freq;
  float s = sinf(ang), c = cosf(ang);
  float qe = row[2 * i], qo = row[2 * i + 1];
  float ke = row[CC + 2 * i], ko = row[CC + 2 * i + 1];
  float qv, kv;
  if ((d & 1) == 0) { qv = qe * c - qo * s; kv = ke * c - ko * s; }
  else              { qv = qe * s + qo * c; kv = ke * s + ko * c; }
  float vv = row[2 * CC + d];
  size_t oi = (((size_t)h * TT + t) << 6) + d;
  qr[oi] = qv; kr[oi] = kv; vr[oi] = vv;
}

// ---- attention: one block per (head, 8-query tile); scores row in LDS (bf16) ----
__global__ __launch_bounds__(256) void k_attn(
    const float* __restrict__ qr, const float* __restrict__ kr,
    const float* __restrict__ vr, u16* __restrict__ out_bf16 /*[T][C]*/) {
  __shared__ u16 sc[QT][TT];          // 32 KB  scores -> probs (bf16)
  __shared__ float qs[QT][DD];        // 2 KB
  __shared__ float pacc[4][QT][DD];   // 8 KB
  __shared__ float invl[QT];

  const int h = blockIdx.y;
  const int qbase = blockIdx.x * QT;
  const int tid = threadIdx.x;
  const float* Qh = qr + ((size_t)h * TT << 6);
  const float* Kh = kr + ((size_t)h * TT << 6);
  const float* Vh = vr + ((size_t)h * TT << 6);

  for (int i = tid; i < QT * DD; i += 256)
    qs[i >> 6][i & 63] = Qh[((size_t)(qbase + (i >> 6)) << 6) + (i & 63)];
  __syncthreads();

  const int nK = qbase + QT;  // multiple of 8
  const float scale = 0.125f; // 1/sqrt(64)

  // phase 1: scores. thread -> key j, all QT queries
  for (int j = tid; j < nK; j += 256) {
    const float4* krow = (const float4*)&Kh[(size_t)j << 6];
    float acc[QT];
#pragma unroll
    for (int qi = 0; qi < QT; qi++) acc[qi] = 0.f;
#pragma unroll
    for (int dc = 0; dc < 16; dc++) {
      float4 kv = krow[dc];
#pragma unroll
      for (int qi = 0; qi < QT; qi++) {
        float4 qv = *(const float4*)&qs[qi][dc * 4];
        acc[qi] += kv.x * qv.x + kv.y * qv.y + kv.z * qv.z + kv.w * qv.w;
      }
    }
#pragma unroll
    for (int qi = 0; qi < QT; qi++) sc[qi][j] = bf16_rne(acc[qi] * scale);
  }
  __syncthreads();

  // phase 2: per-row softmax (wave w handles qi = 2w, 2w+1)
  {
    const int wv = tid >> 6, lane = tid & 63;
    for (int qi = wv * 2; qi < wv * 2 + 2; qi++) {
      const int qpos = qbase + qi;
      float m = -1e30f;
      for (int j = lane; j <= qpos; j += 64) m = fmaxf(m, bf16f(sc[qi][j]));
#pragma unroll
      for (int off = 32; off; off >>= 1) m = fmaxf(m, __shfl_down(m, off));
      m = __shfl(m, 0);
      float l = 0.f;
      for (int j = lane; j < nK; j += 64) {
        float e = 0.f;
        if (j <= qpos) e = __expf(bf16f(sc[qi][j]) - m);
        sc[qi][j] = bf16_rne(e);
        l += e;
      }
#pragma unroll
      for (int off = 32; off; off >>= 1) l += __shfl_down(l, off);
      if (lane == 0) invl[qi] = 1.f / l;
    }
  }
  __syncthreads();

  // phase 3: PV. thread -> (d = tid&63, part = tid>>6); parts take contiguous
  // 4-aligned chunks of the key range (probs are zero where masked/padded).
  {
    const int d = tid & 63, part = tid >> 6;
    const int ng = nK >> 2;            // groups of 4 keys
    const int gpp = (ng + 3) >> 2;     // groups per part
    int g0 = part * gpp, g1 = g0 + gpp; if (g1 > ng) g1 = ng;
    float facc[QT];
#pragma unroll
    for (int qi = 0; qi < QT; qi++) facc[qi] = 0.f;
    for (int g = g0; g < g1; g++) {
      const int j = g << 2;
      float v0 = Vh[((size_t)(j + 0) << 6) + d];
      float v1 = Vh[((size_t)(j + 1) << 6) + d];
      float v2 = Vh[((size_t)(j + 2) << 6) + d];
      float v3 = Vh[((size_t)(j + 3) << 6) + d];
#pragma unroll
      for (int qi = 0; qi < QT; qi++) {
        ushort4 p = *(const ushort4*)&sc[qi][j];
        facc[qi] += bf16f(p.x) * v0 + bf16f(p.y) * v1 + bf16f(p.z) * v2 + bf16f(p.w) * v3;
      }
    }
#pragma unroll
    for (int qi = 0; qi < QT; qi++) pacc[part][qi][d] = facc[qi];
  }
  __syncthreads();

  for (int i = tid; i < QT * DD; i += 256) {
    int qi = i >> 6, dd = i & 63;
    float o = (pacc[0][qi][dd] + pacc[1][qi][dd] + pacc[2][qi][dd] + pacc[3][qi][dd]) * invl[qi];
    out_bf16[(size_t)(qbase + qi) * CC + h * DD + dd] = bf16_rne(o);
  }
}

extern "C" void kernel_launch(void* const* d_in, const int* in_sizes, int n_in,
                              void* d_out, int out_size, void* d_ws, size_t ws_size,
                              hipStream_t stream) {
  const float* x      = (const float*)d_in[0];  // [2048][1024]
  const float* w_qkv  = (const float*)d_in[1];  // [1024][3072]
  const float* w_proj = (const float*)d_in[2];  // [1024][1024]
  float* out = (float*)d_out;                   // [2048][1024] fp32

  // workspace layout (64 MB total)
  char* p = (char*)d_ws;
  u16* xb     = (u16*)p;   p += (size_t)TT * CC * 2;     //  4 MB  x bf16
  u16* wqkvT  = (u16*)p;   p += (size_t)N3 * CC * 2;     //  6 MB  w_qkv^T bf16 [3072][1024]
  u16* wprojT = (u16*)p;   p += (size_t)CC * CC * 2;     //  2 MB  w_proj^T bf16
  float* qkv  = (float*)p; p += (size_t)TT * N3 * 4;     // 24 MB  qkv fp32
  float* qr   = (float*)p; p += (size_t)HH * TT * DD * 4; // 8 MB
  float* kr   = (float*)p; p += (size_t)HH * TT * DD * 4; // 8 MB
  float* vr   = (float*)p; p += (size_t)HH * TT * DD * 4; // 8 MB
  u16* attnb  = (u16*)p;   p += (size_t)TT * CC * 2;     //  4 MB  attn out bf16 [T][C]

  // 1) x -> bf16
  k_cvt_bf16<<<(TT * CC / 4 + 255) / 256, 256, 0, stream>>>(x, xb, TT * CC / 4);
  // 2) weight transposes (fp32 -> bf16, B^T layout for GEMM)
  k_transpose_bf16<<<dim3(N3 / 32, CC / 32), dim3(32, 8), 0, stream>>>(w_qkv, wqkvT, CC, N3);
  k_transpose_bf16<<<dim3(CC / 32, CC / 32), dim3(32, 8), 0, stream>>>(w_proj, wprojT, CC, CC);
  // 3) qkv = x @ w_qkv   (M=2048, N=3072, K=1024)
  k_gemm_bf16<<<dim3(N3 / 64, TT / 64), 256, 0, stream>>>(xb, wqkvT, qkv, TT, N3, CC);
  // 4) RoPE + head reorg
  k_rope<<<(TT * HH * DD + 255) / 256, 256, 0, stream>>>(qkv, qr, kr, vr);
  // 5) causal attention -> bf16 [T][C]
  k_attn<<<dim3(TT / QT, HH), 256, 0, stream>>>(qr, kr, vr, attnb);
  // 6) out = attn @ w_proj (M=2048, N=1024, K=1024)
  k_gemm_bf16<<<dim3(CC / 64, TT / 64), 256, 0, stream>>>(attnb, wprojT, out, TT, CC, CC);
}

// Round 2
// 204.920 us; speedup vs baseline: 4.2888x; 4.2888x over previous
//
#include <hip/hip_runtime.h>
#include <math.h>

// Problem constants (B=1)
#define TT 2048   // sequence length
#define CC 1024   // channels
#define HH 16     // heads
#define DD 64     // head dim
#define N3 3072   // 3*C
#define LDP 72    // padded LDS row length (u16) for 64-wide tiles

typedef unsigned short u16;
typedef __bf16 bf16x8 __attribute__((ext_vector_type(8)));
typedef float f32x4 __attribute__((ext_vector_type(4)));
typedef unsigned short u16x8 __attribute__((ext_vector_type(8)));

__device__ __forceinline__ u16 bf16_rne(float f) {
  unsigned u = __float_as_uint(f);
  u += 0x7FFFu + ((u >> 16) & 1u);
  return (u16)(u >> 16);
}
__device__ __forceinline__ bf16x8 ldfrag(const u16* p) {
  return __builtin_bit_cast(bf16x8, *(const u16x8*)p);
}

// ---- fp32 -> bf16 elementwise (float4 per thread) ----
__global__ void k_cvt_bf16(const float* __restrict__ x, u16* __restrict__ o, int n4) {
  int i = blockIdx.x * blockDim.x + threadIdx.x;
  if (i >= n4) return;
  float4 v = ((const float4*)x)[i];
  ushort4 r;
  r.x = bf16_rne(v.x); r.y = bf16_rne(v.y); r.z = bf16_rne(v.z); r.w = bf16_rne(v.w);
  ((ushort4*)o)[i] = r;
}

// ---- w[K][N] fp32 -> wt[N][K] bf16, 32x32 LDS tile ----
__global__ void k_transpose_bf16(const float* __restrict__ w, u16* __restrict__ wt,
                                 int K, int N) {
  __shared__ u16 tile[32][33];
  int n0 = blockIdx.x * 32, k0 = blockIdx.y * 32;
  int tx = threadIdx.x, ty = threadIdx.y;  // (32, 8)
  for (int r = ty; r < 32; r += 8)
    tile[r][tx] = bf16_rne(w[(size_t)(k0 + r) * N + n0 + tx]);
  __syncthreads();
  for (int r = ty; r < 32; r += 8)
    wt[(size_t)(n0 + r) * K + k0 + tx] = tile[tx][r];
}

// ---- bf16 MFMA GEMM: C[M][N] = A[M][K] * Bt[N][K]^T, fp32 out (64x64 tile) ----
__global__ __launch_bounds__(256) void k_gemm_bf16(
    const u16* __restrict__ A, const u16* __restrict__ Bt,
    float* __restrict__ C, int M, int N, int K) {
  __shared__ u16 As[64][32];
  __shared__ u16 Bs[64][32];
  const int tm = blockIdx.y * 64, tn = blockIdx.x * 64;
  const int tid = threadIdx.x;
  const int lane = tid & 63, wave = tid >> 6;
  const int col = lane & 15, quad = lane >> 4;
  const int srow = tid >> 2, scol = (tid & 3) * 8;

  f32x4 zero = {0.f, 0.f, 0.f, 0.f};
  f32x4 acc[4] = {zero, zero, zero, zero};

  for (int k0 = 0; k0 < K; k0 += 32) {
    *(u16x8*)&As[srow][scol] = *(const u16x8*)&A[(size_t)(tm + srow) * K + k0 + scol];
    *(u16x8*)&Bs[srow][scol] = *(const u16x8*)&Bt[(size_t)(tn + srow) * K + k0 + scol];
    __syncthreads();
    bf16x8 af = ldfrag(&As[wave * 16 + col][quad * 8]);
#pragma unroll
    for (int nt = 0; nt < 4; nt++) {
      bf16x8 bfr = ldfrag(&Bs[nt * 16 + col][quad * 8]);
      acc[nt] = __builtin_amdgcn_mfma_f32_16x16x32_bf16(af, bfr, acc[nt], 0, 0, 0);
    }
    __syncthreads();
  }
#pragma unroll
  for (int nt = 0; nt < 4; nt++)
#pragma unroll
    for (int r = 0; r < 4; r++)
      C[(size_t)(tm + wave * 16 + quad * 4 + r) * N + tn + nt * 16 + col] = acc[nt][r];
}

// ---- RoPE + reorg: qkv[T][3C] -> qr/kr bf16 [H][T][D] ----
__global__ void k_rope(const float* __restrict__ qkv, u16* __restrict__ qr,
                       u16* __restrict__ kr) {
  int idx = blockIdx.x * 256 + threadIdx.x;  // over T*H*D
  if (idx >= TT * HH * DD) return;
  int d = idx & 63;
  int h = (idx >> 6) & 15;
  int t = idx >> 10;
  const float* row = qkv + (size_t)t * N3 + h * DD;
  int i = d >> 1;
  float inv_freq = exp2f(-(float)(2 * i) * (1.0f / 64.0f) * 13.2877123795494f); // log2(1e4)
  float ang = (float)t * inv_freq;
  float s = sinf(ang), c = cosf(ang);
  float qe = row[2 * i], qo = row[2 * i + 1];
  float ke = row[CC + 2 * i], ko = row[CC + 2 * i + 1];
  float qv, kv;
  if ((d & 1) == 0) { qv = qe * c - qo * s; kv = ke * c - ko * s; }
  else              { qv = qe * s + qo * c; kv = ke * s + ko * c; }
  size_t oi = (((size_t)h * TT + t) << 6) + d;
  qr[oi] = bf16_rne(qv); kr[oi] = bf16_rne(kv);
}

// ---- V transpose: qkv[T][3C] v-slice -> vt bf16 [H][D][T] ----
__global__ void k_vtrans(const float* __restrict__ qkv, u16* __restrict__ vt) {
  __shared__ float tile[32][33];
  int t0 = blockIdx.x * 32, d0 = blockIdx.y * 32, h = blockIdx.z;
  int tx = threadIdx.x, ty = threadIdx.y;  // (32, 8)
  for (int r = ty; r < 32; r += 8)
    tile[r][tx] = qkv[(size_t)(t0 + r) * N3 + 2 * CC + h * DD + d0 + tx];
  __syncthreads();
  for (int r = ty; r < 32; r += 8)
    vt[((size_t)h * DD + d0 + r) * TT + t0 + tx] = bf16_rne(tile[tx][r]);
}

// ---- flash attention: block = (q-tile 64, head); 4 waves x 16-query strip ----
// MFMA 16x16x32 bf16. A/B frag: [m|n = lane&15][k = quad*8+j]; C/D: col=lane&15,
// row=quad*4+reg. P transits LDS (wave-private region, no barrier needed).
__global__ __launch_bounds__(256) void k_flash(
    const u16* __restrict__ qr, const u16* __restrict__ kr,
    const u16* __restrict__ vt, u16* __restrict__ outb /*[T][C]*/) {
  __shared__ u16 Qs[64 * LDP];
  __shared__ u16 Ks[64 * LDP];
  __shared__ u16 Vs[64 * LDP];
  __shared__ u16 Ps[64 * LDP];

  const int h = blockIdx.y;
  const int bx = blockIdx.x;
  // pair big+small q-tiles for load balance (tile qt does qt+1 key-tiles)
  const int qt = (bx & 1) ? (31 - (bx >> 1)) : (bx >> 1);
  const int q0 = qt * 64;
  const int tid = threadIdx.x;
  const int lane = tid & 63, wv = tid >> 6;
  const int col = lane & 15, quad = lane >> 4;

  const u16* Qh = qr + (size_t)h * TT * DD;
  const u16* Kh = kr + (size_t)h * TT * DD;
  const u16* Vh = vt + (size_t)h * DD * TT;  // [d][t]

  // stage Q tile (64x64 bf16)
  {
    int r = tid >> 2, c0 = (tid & 3) * 16;
    *(u16x8*)&Qs[r * LDP + c0]     = *(const u16x8*)&Qh[(size_t)(q0 + r) * DD + c0];
    *(u16x8*)&Qs[r * LDP + c0 + 8] = *(const u16x8*)&Qh[(size_t)(q0 + r) * DD + c0 + 8];
  }
  __syncthreads();

  // Q A-frags, fixed across the K loop
  const bf16x8 aq0 = ldfrag(&Qs[(wv * 16 + col) * LDP + quad * 8]);
  const bf16x8 aq1 = ldfrag(&Qs[(wv * 16 + col) * LDP + 32 + quad * 8]);

  const f32x4 zero = {0.f, 0.f, 0.f, 0.f};
  f32x4 acc[4] = {zero, zero, zero, zero};
  float mrun[4] = {-1e30f, -1e30f, -1e30f, -1e30f};
  float lrun[4] = {0.f, 0.f, 0.f, 0.f};

  for (int kt = 0; kt <= qt; kt++) {
    const int k0 = kt * 64;
    {
      int r = tid >> 2, c0 = (tid & 3) * 16;
      *(u16x8*)&Ks[r * LDP + c0]     = *(const u16x8*)&Kh[(size_t)(k0 + r) * DD + c0];
      *(u16x8*)&Ks[r * LDP + c0 + 8] = *(const u16x8*)&Kh[(size_t)(k0 + r) * DD + c0 + 8];
      *(u16x8*)&Vs[r * LDP + c0]     = *(const u16x8*)&Vh[(size_t)r * TT + k0 + c0];
      *(u16x8*)&Vs[r * LDP + c0 + 8] = *(const u16x8*)&Vh[(size_t)r * TT + k0 + c0 + 8];
    }
    __syncthreads();

    // S = Q K^T : per wave 16q x 64k
    f32x4 s[4];
#pragma unroll
    for (int nt = 0; nt < 4; nt++) {
      bf16x8 bk0 = ldfrag(&Ks[(nt * 16 + col) * LDP + quad * 8]);
      bf16x8 bk1 = ldfrag(&Ks[(nt * 16 + col) * LDP + 32 + quad * 8]);
      s[nt] = __builtin_amdgcn_mfma_f32_16x16x32_bf16(aq0, bk0, zero, 0, 0, 0);
      s[nt] = __builtin_amdgcn_mfma_f32_16x16x32_bf16(aq1, bk1, s[nt], 0, 0, 0);
    }
#pragma unroll
    for (int nt = 0; nt < 4; nt++) s[nt] *= 0.125f;  // 1/sqrt(64)

    if (kt == qt) {  // diagonal tile: causal mask (local indices, since k0==q0)
#pragma unroll
      for (int nt = 0; nt < 4; nt++)
#pragma unroll
        for (int r = 0; r < 4; r++)
          if (nt * 16 + col > wv * 16 + quad * 4 + r) s[nt][r] = -1e30f;
    }

    // online softmax: rows = quad*4+r, cols spread over 16 lanes of the quad
    float rm[4];
#pragma unroll
    for (int r = 0; r < 4; r++)
      rm[r] = fmaxf(fmaxf(s[0][r], s[1][r]), fmaxf(s[2][r], s[3][r]));
#pragma unroll
    for (int o = 1; o < 16; o <<= 1)
#pragma unroll
      for (int r = 0; r < 4; r++) rm[r] = fmaxf(rm[r], __shfl_xor(rm[r], o));

    float alpha[4];
#pragma unroll
    for (int r = 0; r < 4; r++) {
      float mn = fmaxf(mrun[r], rm[r]);
      alpha[r] = __expf(mrun[r] - mn);
      mrun[r] = mn;
    }
#pragma unroll
    for (int nt = 0; nt < 4; nt++)
#pragma unroll
      for (int r = 0; r < 4; r++) acc[nt][r] *= alpha[r];

    float rs[4] = {0.f, 0.f, 0.f, 0.f};
#pragma unroll
    for (int nt = 0; nt < 4; nt++)
#pragma unroll
      for (int r = 0; r < 4; r++) {
        float p = __expf(s[nt][r] - mrun[r]);
        s[nt][r] = p;
        rs[r] += p;
      }
#pragma unroll
    for (int o = 1; o < 16; o <<= 1)
#pragma unroll
      for (int r = 0; r < 4; r++) rs[r] += __shfl_xor(rs[r], o);
#pragma unroll
    for (int r = 0; r < 4; r++) lrun[r] = lrun[r] * alpha[r] + rs[r];

    // P -> LDS (C-layout scatter, bf16), wave-private rows
#pragma unroll
    for (int nt = 0; nt < 4; nt++)
#pragma unroll
      for (int r = 0; r < 4; r++)
        Ps[(wv * 16 + quad * 4 + r) * LDP + nt * 16 + col] = bf16_rne(s[nt][r]);

    // O += P V^T
#pragma unroll
    for (int kk = 0; kk < 2; kk++) {
      bf16x8 ap = ldfrag(&Ps[(wv * 16 + col) * LDP + kk * 32 + quad * 8]);
#pragma unroll
      for (int nt = 0; nt < 4; nt++) {
        bf16x8 bv = ldfrag(&Vs[(nt * 16 + col) * LDP + kk * 32 + quad * 8]);
        acc[nt] = __builtin_amdgcn_mfma_f32_16x16x32_bf16(ap, bv, acc[nt], 0, 0, 0);
      }
    }
    __syncthreads();
  }

  // epilogue: normalize, write bf16 [T][C]
  float inv[4];
#pragma unroll
  for (int r = 0; r < 4; r++) inv[r] = 1.f / lrun[r];
#pragma unroll
  for (int nt = 0; nt < 4; nt++)
#pragma unroll
    for (int r = 0; r < 4; r++) {
      int q = q0 + wv * 16 + quad * 4 + r;
      outb[(size_t)q * CC + h * DD + nt * 16 + col] = bf16_rne(acc[nt][r] * inv[r]);
    }
}

extern "C" void kernel_launch(void* const* d_in, const int* in_sizes, int n_in,
                              void* d_out, int out_size, void* d_ws, size_t ws_size,
                              hipStream_t stream) {
  const float* x      = (const float*)d_in[0];  // [2048][1024]
  const float* w_qkv  = (const float*)d_in[1];  // [1024][3072]
  const float* w_proj = (const float*)d_in[2];  // [1024][1024]
  float* out = (float*)d_out;                   // [2048][1024] fp32

  char* p = (char*)d_ws;
  u16* xb     = (u16*)p;   p += (size_t)TT * CC * 2;       //  4 MB
  u16* wqkvT  = (u16*)p;   p += (size_t)N3 * CC * 2;       //  6 MB
  u16* wprojT = (u16*)p;   p += (size_t)CC * CC * 2;       //  2 MB
  float* qkv  = (float*)p; p += (size_t)TT * N3 * 4;       // 24 MB
  u16* qr     = (u16*)p;   p += (size_t)HH * TT * DD * 2;  //  4 MB
  u16* kr     = (u16*)p;   p += (size_t)HH * TT * DD * 2;  //  4 MB
  u16* vt     = (u16*)p;   p += (size_t)HH * DD * TT * 2;  //  4 MB
  u16* attnb  = (u16*)p;   p += (size_t)TT * CC * 2;       //  4 MB

  k_cvt_bf16<<<(TT * CC / 4 + 255) / 256, 256, 0, stream>>>(x, xb, TT * CC / 4);
  k_transpose_bf16<<<dim3(N3 / 32, CC / 32), dim3(32, 8), 0, stream>>>(w_qkv, wqkvT, CC, N3);
  k_transpose_bf16<<<dim3(CC / 32, CC / 32), dim3(32, 8), 0, stream>>>(w_proj, wprojT, CC, CC);
  k_gemm_bf16<<<dim3(N3 / 64, TT / 64), 256, 0, stream>>>(xb, wqkvT, qkv, TT, N3, CC);
  k_rope<<<(TT * HH * DD + 255) / 256, 256, 0, stream>>>(qkv, qr, kr);
  k_vtrans<<<dim3(TT / 32, DD / 32, HH), dim3(32, 8), 0, stream>>>(qkv, vt);
  k_flash<<<dim3(TT / 64, HH), 256, 0, stream>>>(qr, kr, vt, attnb);
  k_gemm_bf16<<<dim3(CC / 64, TT / 64), 256, 0, stream>>>(attnb, wprojT, out, TT, CC, CC);
}